// Round 2
// 476.115 us; speedup vs baseline: 1.0253x; 1.0253x over previous
//
#include <hip/hip_runtime.h>
#include <hip/hip_bf16.h>
#include <math.h>

typedef __bf16 bf16;
typedef __attribute__((ext_vector_type(8))) __bf16 bf16x8;
typedef __attribute__((ext_vector_type(4))) __bf16 bf16x4;
typedef __attribute__((ext_vector_type(4))) float f32x4;

#define MFMA16(a, b, c) __builtin_amdgcn_mfma_f32_16x16x32_bf16(a, b, c, 0, 0, 0)

// async global->LDS, 16B per lane; lds dest must be wave-uniform base
// (HW writes base + lane*16) -- LDS tiles are therefore UNPADDED/linear.
__device__ __forceinline__ void load16_lds(const bf16* g, bf16* l) {
  __builtin_amdgcn_global_load_lds(
      (const __attribute__((address_space(1))) void*)g,
      (__attribute__((address_space(3))) void*)l, 16, 0, 0);
}

// ---------------------------------------------------------------------------
// fp32 -> bf16 cast (hidden_states), 8 elems/thread
// ---------------------------------------------------------------------------
__global__ __launch_bounds__(256) void cast_k(const float* __restrict__ src,
                                              bf16* __restrict__ dst) {
  const size_t i = ((size_t)blockIdx.x * 256 + threadIdx.x) * 8;
  f32x4 a = *(const f32x4*)(src + i);
  f32x4 b = *(const f32x4*)(src + i + 4);
  bf16x8 h;
#pragma unroll
  for (int j = 0; j < 4; ++j) {
    h[j] = (bf16)a[j];
    h[4 + j] = (bf16)b[j];
  }
  *(bf16x8*)(dst + i) = h;
}

// ---------------------------------------------------------------------------
// Transpose + cast: src [rows][cols] fp32 -> dst [cols][rows] bf16.
// ---------------------------------------------------------------------------
__global__ __launch_bounds__(256) void transpose_cast_k(
    const float* __restrict__ src, bf16* __restrict__ dst, int rows,
    int cols) {
  __shared__ float tile[64][65];
  const int c0 = blockIdx.x * 64, r0 = blockIdx.y * 64;
  const int tid = threadIdx.x;
  const int lr = tid >> 4;          // 0..15
  const int lc = (tid & 15) * 4;    // 0..60
#pragma unroll
  for (int i = 0; i < 4; ++i) {
    const int row = lr + i * 16;
    const f32x4 v = *(const f32x4*)&src[(size_t)(r0 + row) * cols + c0 + lc];
#pragma unroll
    for (int j = 0; j < 4; ++j) tile[row][lc + j] = v[j];
  }
  __syncthreads();
#pragma unroll
  for (int i = 0; i < 4; ++i) {
    const int orow = lr + i * 16;  // = src col index within tile
    bf16x4 h;
#pragma unroll
    for (int j = 0; j < 4; ++j) h[j] = (bf16)tile[lc + j][orow];
    *(bf16x4*)&dst[(size_t)(c0 + orow) * rows + r0 + lc] = h;
  }
}

// ---------------------------------------------------------------------------
// 256x256 8-phase QKV GEMM (T2+T3+T4+T5 per m201 template), K=4096 baked.
// C = A[2048 x 4096] @ Bt[6144 x 4096]^T, fused QKV epilogue:
//   cols <4096 -> Cq[2048][4096]; <5120 -> Ck[2048][1024];
//   else       -> Cv transposed  [1024][2048].
//
// 512 thr = 8 waves (2M x 4N), 128x64 output per wave, BK=64, 2 K-tiles/iter.
// LDS 128 KiB: As[2][256*64] + Bs[2][256*64] (double-buffered, LINEAR dest).
// Swizzle: read elem-off ^= (row&7)<<3  (16B granule); staging pre-swizzles
// the GLOBAL source chunk (c ^ row&7) so global_load_lds dest stays linear
// (both-sides-or-neither, same involution).
//
// Prefetch-issue safety (per iteration, tiles t0=2i->buf0, t1=2i+1->buf1):
//   buf0.B last read ph2  -> stage (t0+2).B at ph3
//   buf0.A last read ph3  -> stage (t0+2).A at ph4
//   buf1.B last read ph6  -> stage (t1+2).B at ph7
//   buf1.A last read ph7  -> stage (t1+2).A at ph8
// vmcnt(6) at ph4/ph8 (= 3 half-tiles in flight) guarantees the next-needed
// buffer fully landed before its barrier. Never vmcnt(0) in the loop.
// sched_barrier(0) after every waitcnt pins compiler ordering (rule #18).
// ---------------------------------------------------------------------------
#define BARX() __builtin_amdgcn_s_barrier()
#define SBAR0() __builtin_amdgcn_sched_barrier(0)
#define LGKM0()                                       \
  {                                                   \
    asm volatile("s_waitcnt lgkmcnt(0)" ::: "memory");\
    SBAR0();                                          \
  }
#define VMC(N)                                          \
  {                                                     \
    asm volatile("s_waitcnt vmcnt(" #N ")" ::: "memory");\
    SBAR0();                                            \
  }

#define DS_A(BUF, QM)                                                       \
  {                                                                         \
    _Pragma("unroll") for (int mi = 0; mi < 4; ++mi)                        \
        _Pragma("unroll") for (int kk = 0; kk < 2; ++kk)                    \
            a[mi][kk] = *(const bf16x8*)&As[BUF][(aBase ^ (kk << 5)) +      \
                                                (QM)*4096 + mi * 1024];     \
  }

#define DS_B(BUF, QN, BR)                                                   \
  {                                                                         \
    _Pragma("unroll") for (int ni = 0; ni < 2; ++ni)                        \
        _Pragma("unroll") for (int kk = 0; kk < 2; ++kk)                    \
            BR[ni][kk] = *(const bf16x8*)&Bs[BUF][(bBase ^ (kk << 5)) +     \
                                                  (QN)*2048 + ni * 1024];   \
  }

#define MMAC(QM, QN, BR)                                                    \
  {                                                                         \
    __builtin_amdgcn_s_setprio(1);                                          \
    _Pragma("unroll") for (int mi = 0; mi < 4; ++mi)                        \
        _Pragma("unroll") for (int ni = 0; ni < 2; ++ni) {                  \
      acc[(QM)*4 + mi][(QN)*2 + ni] =                                       \
          MFMA16(a[mi][0], BR[ni][0], acc[(QM)*4 + mi][(QN)*2 + ni]);       \
      acc[(QM)*4 + mi][(QN)*2 + ni] =                                       \
          MFMA16(a[mi][1], BR[ni][1], acc[(QM)*4 + mi][(QN)*2 + ni]);       \
    }                                                                       \
    __builtin_amdgcn_s_setprio(0);                                          \
  }

#define STAGE_A(BUF, T)                                                     \
  {                                                                         \
    const bf16* g0 = aS0 + (size_t)(T)*64;                                  \
    const bf16* g1 = aS1 + (size_t)(T)*64;                                  \
    bf16* l = &As[BUF][w * 512];                                            \
    load16_lds(g0, l);                                                      \
    load16_lds(g1, l + 4096);                                               \
    load16_lds(g0 + ROWK128, l + 8192);                                     \
    load16_lds(g1 + ROWK128, l + 12288);                                    \
  }

#define STAGE_B(BUF, T)                                                     \
  {                                                                         \
    const bf16* g0 = bS0 + (size_t)(T)*64;                                  \
    const bf16* g1 = bS1 + (size_t)(T)*64;                                  \
    bf16* l = &Bs[BUF][w * 512];                                            \
    load16_lds(g0, l);                                                      \
    load16_lds(g1, l + 4096);                                               \
    load16_lds(g0 + ROWK128, l + 8192);                                     \
    load16_lds(g1 + ROWK128, l + 12288);                                    \
  }

__global__ __launch_bounds__(512, 2) void gemm_qkv256(
    const bf16* __restrict__ A, const bf16* __restrict__ Bt,
    bf16* __restrict__ Cq, bf16* __restrict__ Ck, bf16* __restrict__ Cv) {
  constexpr int K = 4096;
  constexpr size_t ROWK128 = (size_t)128 * K;
  __shared__ bf16 As[2][256 * 64];
  __shared__ bf16 Bs[2][256 * 64];

  const int tid = threadIdx.x;
  const int lane = tid & 63;
  const int w = tid >> 6;   // 0..7
  const int wm = w >> 2;    // 0..1
  const int wn = w & 3;     // 0..3
  const int quad = lane >> 4;
  const int m16 = lane & 15;

  const int rowBase = blockIdx.y * 256;
  const int colBase = blockIdx.x * 256;

  // staging source map (pre-swizzled): u = chunk id; row=u>>3, chunk=u&7,
  // src chunk = (u&7) ^ (row&7). Same 128B segment -> fully coalesced.
  const int u0 = tid, u1 = 512 + tid;
  const int r0 = u0 >> 3, c0s = (u0 & 7) ^ (r0 & 7);
  const int r1 = u1 >> 3, c1s = (u1 & 7) ^ (r1 & 7);
  const bf16* aS0 = A + (size_t)(rowBase + r0) * K + c0s * 8;
  const bf16* aS1 = A + (size_t)(rowBase + r1) * K + c1s * 8;
  const bf16* bS0 = Bt + (size_t)(colBase + r0) * K + c0s * 8;
  const bf16* bS1 = Bt + (size_t)(colBase + r1) * K + c1s * 8;

  // read-side swizzled bases: row&7 == m16&7 for every fragment row
  const int xsw = (m16 & 7) << 3;
  const int ko0 = (quad * 8) ^ xsw;
  const int aBase = (wm * 128 + m16) * 64 + ko0;
  const int bBase = (wn * 64 + m16) * 64 + ko0;

  f32x4 acc[8][4];
#pragma unroll
  for (int i = 0; i < 8; ++i)
#pragma unroll
    for (int j = 0; j < 4; ++j) acc[i][j] = (f32x4){0.f, 0.f, 0.f, 0.f};

  bf16x8 a[4][2], b0[2][2], b1[2][2];

  // prologue: tile0 -> buf0 (8 loads), tile1 -> buf1 (8 loads)
  STAGE_A(0, 0);
  STAGE_B(0, 0);
  STAGE_A(1, 1);
  STAGE_B(1, 1);
  VMC(8);  // tile0 landed; tile1 may stay in flight (gated at ph4)
  BARX();

  constexpr int nT = K / 64;  // 64 K-tiles, 32 iterations
#pragma unroll 1
  for (int i = 0; i < nT / 2; ++i) {
    const int p0 = (2 * i + 2 < nT) ? 2 * i + 2 : 0;  // clamp: data unused
    const int p1 = (2 * i + 3 < nT) ? 2 * i + 3 : 0;
    // ---- phase 1: A(qm0)+B(qn0) of buf0 ----
    DS_A(0, 0);
    DS_B(0, 0, b0);
    BARX();
    LGKM0();
    MMAC(0, 0, b0);
    BARX();
    // ---- phase 2: B(qn1) ----
    DS_B(0, 1, b1);
    BARX();
    LGKM0();
    MMAC(0, 1, b1);
    BARX();
    // ---- phase 3: A(qm1); prefetch B of tile t0+2 -> buf0.B (free since ph2)
    DS_A(0, 1);
    STAGE_B(0, p0);
    BARX();
    LGKM0();
    MMAC(1, 0, b0);
    BARX();
    // ---- phase 4: prefetch A -> buf0.A (free since ph3); counted vmcnt ----
    STAGE_A(0, p0);
    VMC(6);  // all of tile t1 landed; 3 half-tiles remain in flight
    BARX();
    MMAC(1, 1, b1);
    BARX();
    // ---- phase 5: buf1 ----
    DS_A(1, 0);
    DS_B(1, 0, b0);
    BARX();
    LGKM0();
    MMAC(0, 0, b0);
    BARX();
    // ---- phase 6 ----
    DS_B(1, 1, b1);
    BARX();
    LGKM0();
    MMAC(0, 1, b1);
    BARX();
    // ---- phase 7: prefetch B of t1+2 -> buf1.B ----
    DS_A(1, 1);
    STAGE_B(1, p1);
    BARX();
    LGKM0();
    MMAC(1, 0, b0);
    BARX();
    // ---- phase 8 ----
    STAGE_A(1, p1);
    VMC(6);  // all of tile t0+2 landed before next ph1
    BARX();
    MMAC(1, 1, b1);
    BARX();
  }
  VMC(0);  // drain tail prefetches before epilogue/end

  // epilogue: C/D layout col = lane&15, row = quad*4 + reg
#pragma unroll
  for (int am = 0; am < 8; ++am) {
    const int gr0 = rowBase + wm * 128 + am * 16 + quad * 4;
#pragma unroll
    for (int an = 0; an < 4; ++an) {
      const int gc = colBase + wn * 64 + an * 16 + m16;
      if (colBase < 4096) {  // Q -> qbuf [2048][4096]
#pragma unroll
        for (int r = 0; r < 4; ++r)
          Cq[(size_t)(gr0 + r) * 4096 + gc] = (bf16)acc[am][an][r];
      } else if (colBase < 5120) {  // K -> kbuf [2048][1024]
#pragma unroll
        for (int r = 0; r < 4; ++r)
          Ck[(size_t)(gr0 + r) * 1024 + (gc - 4096)] = (bf16)acc[am][an][r];
      } else {  // V -> vT [1024][2048]
        bf16x4 h;
#pragma unroll
        for (int r = 0; r < 4; ++r) h[r] = (bf16)acc[am][an][r];
        *(bf16x4*)&Cv[(size_t)(gc - 5120) * 2048 + gr0] = h;
      }
    }
  }
}

// ---------------------------------------------------------------------------
// m97-style GEMM kept for the output projection (EPI==0 path only).
// ---------------------------------------------------------------------------
template <typename OT, int EPI>
__global__ __launch_bounds__(256, 2) void gemm_bt(const bf16* __restrict__ A,
                                                  const bf16* __restrict__ Bt,
                                                  OT* __restrict__ C,
                                                  bf16* __restrict__ Ck,
                                                  bf16* __restrict__ C2, int M,
                                                  int N, int K, int ldc) {
  __shared__ bf16 As[128 * 32];
  __shared__ bf16 Bs[128 * 32];

  const int tid = threadIdx.x;
  const int lane = tid & 63;
  const int w = tid >> 6;
  const int quad = lane >> 4;
  const int m16 = lane & 15;
  const int wr = (w >> 1) * 64;
  const int wc = (w & 1) * 64;
  const int rowBase = blockIdx.y * 128;
  const int colBase = blockIdx.x * 128;

  f32x4 acc[4][4];
#pragma unroll
  for (int i = 0; i < 4; ++i)
#pragma unroll
    for (int j = 0; j < 4; ++j) acc[i][j] = (f32x4){0.f, 0.f, 0.f, 0.f};

  const int u1 = w * 128 + lane;
  const int u2 = u1 + 64;
  const int r1 = u1 >> 2, s1 = (u1 & 3) * 8;
  const int r2 = u2 >> 2, s2 = (u2 & 3) * 8;
  const bf16* aG1 = A + (size_t)(rowBase + r1) * K + s1;
  const bf16* aG2 = A + (size_t)(rowBase + r2) * K + s2;
  const bf16* bG1 = Bt + (size_t)(colBase + r1) * K + s1;
  const bf16* bG2 = Bt + (size_t)(colBase + r2) * K + s2;
  bf16* const lA1 = As + (size_t)(w * 128) * 8;
  bf16* const lA2 = As + (size_t)(w * 128 + 64) * 8;
  bf16* const lB1 = Bs + (size_t)(w * 128) * 8;
  bf16* const lB2 = Bs + (size_t)(w * 128 + 64) * 8;

  for (int k0 = 0; k0 < K; k0 += 32) {
    load16_lds(aG1 + k0, lA1);
    load16_lds(aG2 + k0, lA2);
    load16_lds(bG1 + k0, lB1);
    load16_lds(bG2 + k0, lB2);
    __syncthreads();

    bf16x8 af[4], bfr[4];
#pragma unroll
    for (int mi = 0; mi < 4; ++mi)
      af[mi] = *(const bf16x8*)&As[(wr + mi * 16 + m16) * 32 + quad * 8];
#pragma unroll
    for (int ni = 0; ni < 4; ++ni)
      bfr[ni] = *(const bf16x8*)&Bs[(wc + ni * 16 + m16) * 32 + quad * 8];
#pragma unroll
    for (int mi = 0; mi < 4; ++mi)
#pragma unroll
      for (int ni = 0; ni < 4; ++ni)
        acc[mi][ni] = MFMA16(af[mi], bfr[ni], acc[mi][ni]);
    __syncthreads();
  }

#pragma unroll
  for (int mi = 0; mi < 4; ++mi) {
#pragma unroll
    for (int ni = 0; ni < 4; ++ni) {
      const int gr0 = rowBase + wr + mi * 16 + quad * 4;
      const int gc = colBase + wc + ni * 16 + m16;
      if constexpr (EPI == 0) {
#pragma unroll
        for (int r = 0; r < 4; ++r)
          C[(size_t)(gr0 + r) * ldc + gc] = (OT)acc[mi][ni][r];
      }
    }
  }
}

// ---------------------------------------------------------------------------
// RoPE (rotate-half, in place). Fast transcendentals: powf -> __expf with
// constant-folded log, sincosf -> __sincosf.
// ---------------------------------------------------------------------------
__global__ __launch_bounds__(256) void rope_k(bf16* __restrict__ qb,
                                              bf16* __restrict__ kb) {
  const int NQTOT = 2048 * 32 * 64;
  const int NKTOT = 2048 * 8 * 64;
  int idx = blockIdx.x * 256 + threadIdx.x;
  bf16* buf;
  int nh, rest;
  if (idx < NQTOT) {
    buf = qb;
    nh = 32;
    rest = idx;
  } else {
    rest = idx - NQTOT;
    if (rest >= NKTOT) return;
    buf = kb;
    nh = 8;
  }
  const int j = rest & 63;
  const int hs = rest >> 6;
  const int hh = hs % nh;
  const int s = hs / nh;
  // 10000^(-j/64) = exp(-j * ln(10000)/64)
  const float inv = __expf((float)j * -0.14391157f);
  const float f = (float)s * inv;
  float sn, cs;
  __sincosf(f, &sn, &cs);
  const size_t base = (size_t)(s * nh + hh) * 128 + j;
  const float x1 = (float)buf[base];
  const float x2 = (float)buf[base + 64];
  buf[base] = (bf16)(x1 * cs - x2 * sn);
  buf[base + 64] = (bf16)(x2 * cs + x1 * sn);
}

// ---------------------------------------------------------------------------
// Flash attention, streaming (sink + local) mask — unchanged this round.
// ---------------------------------------------------------------------------
__global__ __launch_bounds__(256, 2) void attn_k(const bf16* __restrict__ q,
                                                 const bf16* __restrict__ kbuf,
                                                 const bf16* __restrict__ vT,
                                                 bf16* __restrict__ attn) {
  const int qb = 15 - blockIdx.x;
  const int h = blockIdx.y;
  const int kvh = h >> 2;
  const int tid = threadIdx.x;
  const int lane = tid & 63;
  const int w = tid >> 6;
  const int quad = lane >> 4;
  const int m16 = lane & 15;

  __shared__ bf16 Ks[4][64 * 32];
  __shared__ bf16 Vs[2][128 * 32];
  __shared__ bf16 Ps[128][72];

  const int qrow0 = qb * 128 + w * 32;

  bf16x8 qf[2][4];
#pragma unroll
  for (int rt = 0; rt < 2; ++rt)
#pragma unroll
    for (int kt = 0; kt < 4; ++kt)
      qf[rt][kt] = *(const bf16x8*)&q[(size_t)(qrow0 + rt * 16 + m16) * 4096 +
                                      h * 128 + kt * 32 + quad * 8];

  f32x4 o[2][8];
  float lsum[2][4];
#pragma unroll
  for (int rt = 0; rt < 2; ++rt) {
#pragma unroll
    for (int dt = 0; dt < 8; ++dt) o[rt][dt] = (f32x4){0.f, 0.f, 0.f, 0.f};
#pragma unroll
    for (int r = 0; r < 4; ++r) lsum[rt][r] = 0.f;
  }

  const float scale = 0.08838834764831845f;  // 1/sqrt(128)
  const bf16* kbase = kbuf + kvh * 128;
  const bf16* vbase = vT + (size_t)(kvh * 128) * 2048;

  const int klocal = (lane >> 2);
  const int kseg = (lane & 3) * 8;

  for (int b = 0; b <= qb; ++b) {
    if (b > 0 && (qb - b) >= 8) continue;  // streaming mask: sink or local
    const bool diag = (b == qb);
    for (int half = 0; half < 2; ++half) {
      const int gk0 = b * 128 + half * 64;

#pragma unroll
      for (int i = 0; i < 4; ++i) {
        const int j = w * 4 + i;
        const int kt = j >> 2, grp = (j & 3) * 16;
        load16_lds(kbase + (size_t)(gk0 + grp + klocal) * 1024 + kt * 32 + kseg,
                   &Ks[kt][grp * 32]);
      }
#pragma unroll
      for (int i = 0; i < 4; ++i) {
        const int j = w * 4 + i;
        const int kc = j >> 3, grp = (j & 7) * 16;
        load16_lds(vbase + (size_t)(grp + klocal) * 2048 + gk0 + kc * 32 + kseg,
                   &Vs[kc][grp * 32]);
      }
      __syncthreads();

      const bool skip = diag && (half * 64 > w * 32 + 31);
      if (!skip) {
        f32x4 sc[2][4];
#pragma unroll
        for (int rt = 0; rt < 2; ++rt)
#pragma unroll
          for (int ct = 0; ct < 4; ++ct)
            sc[rt][ct] = (f32x4){0.f, 0.f, 0.f, 0.f};
#pragma unroll
        for (int kt = 0; kt < 4; ++kt) {
          bf16x8 kf[4];
#pragma unroll
          for (int ct = 0; ct < 4; ++ct)
            kf[ct] = *(const bf16x8*)&Ks[kt][(ct * 16 + m16) * 32 + quad * 8];
#pragma unroll
          for (int rt = 0; rt < 2; ++rt)
#pragma unroll
            for (int ct = 0; ct < 4; ++ct)
              sc[rt][ct] = MFMA16(qf[rt][kt], kf[ct], sc[rt][ct]);
        }

#pragma unroll
        for (int rt = 0; rt < 2; ++rt)
#pragma unroll
          for (int ct = 0; ct < 4; ++ct)
#pragma unroll
            for (int r = 0; r < 4; ++r) {
              float p = __expf(sc[rt][ct][r] * scale);
              if (diag) {
                const int colg = gk0 + ct * 16 + m16;
                const int rowg = qrow0 + rt * 16 + quad * 4 + r;
                if (colg > rowg) p = 0.f;
              }
              lsum[rt][r] += p;
              Ps[w * 32 + rt * 16 + quad * 4 + r][ct * 16 + m16] = (bf16)p;
            }

#pragma unroll
        for (int rt = 0; rt < 2; ++rt)
#pragma unroll
          for (int kc = 0; kc < 2; ++kc) {
            const bf16x8 pa =
                *(const bf16x8*)&Ps[w * 32 + rt * 16 + m16][kc * 32 + quad * 8];
#pragma unroll
            for (int dt = 0; dt < 8; ++dt) {
              const bf16x8 vb =
                  *(const bf16x8*)&Vs[kc][(dt * 16 + m16) * 32 + quad * 8];
              o[rt][dt] = MFMA16(pa, vb, o[rt][dt]);
            }
          }
      }
      __syncthreads();
    }
  }

#pragma unroll
  for (int rt = 0; rt < 2; ++rt) {
    float inv[4];
#pragma unroll
    for (int r = 0; r < 4; ++r) {
      float s = lsum[rt][r];
      s += __shfl_xor(s, 1);
      s += __shfl_xor(s, 2);
      s += __shfl_xor(s, 4);
      s += __shfl_xor(s, 8);
      inv[r] = 1.0f / s;
    }
#pragma unroll
    for (int dt = 0; dt < 8; ++dt)
#pragma unroll
      for (int r = 0; r < 4; ++r)
        attn[(size_t)(qrow0 + rt * 16 + quad * 4 + r) * 4096 + h * 128 +
             dt * 16 + m16] = (bf16)(o[rt][dt][r] * inv[r]);
  }
}

// ---------------------------------------------------------------------------
// Workspace layout (88 MB; aliasing is stream-order safe):
//   off   0 MB: hiddenB (16MB)            -- dead after QKV gemm
//   off  16 MB: wqkvT  (48MB = q|k|v)     -- dead after QKV gemm
//       woT (32MB) later at off 0  (overwrites hiddenB + wqkvT head)
//       attnb (16MB) later at off 32 (overwrites wqkvT middle)
//   off  64 MB: qbuf (16MB)
//   off  80 MB: kbuf (4MB)
//   off  84 MB: vT  (4MB)
// ---------------------------------------------------------------------------
extern "C" void kernel_launch(void* const* d_in, const int* in_sizes, int n_in,
                              void* d_out, int out_size, void* d_ws,
                              size_t ws_size, hipStream_t stream) {
  const float* hidden = (const float*)d_in[0];
  const float* wq = (const float*)d_in[1];
  const float* wk = (const float*)d_in[2];
  const float* wv = (const float*)d_in[3];
  const float* wo = (const float*)d_in[4];
  float* out = (float*)d_out;

  const size_t MB = 1024 * 1024;
  bf16* hiddenB = (bf16*)d_ws;
  bf16* wqkvT = (bf16*)((char*)d_ws + 16 * MB);
  bf16* woT = (bf16*)d_ws;
  bf16* attnb = (bf16*)((char*)d_ws + 32 * MB);
  bf16* qbuf = (bf16*)((char*)d_ws + 64 * MB);
  bf16* kbuf = (bf16*)((char*)d_ws + 80 * MB);
  bf16* vT = (bf16*)((char*)d_ws + 84 * MB);

  // --- one-time casts/transposes ---
  cast_k<<<4096, 256, 0, stream>>>(hidden, hiddenB);
  transpose_cast_k<<<dim3(64, 64), 256, 0, stream>>>(wq, wqkvT, 4096, 4096);
  transpose_cast_k<<<dim3(16, 64), 256, 0, stream>>>(
      wk, wqkvT + (size_t)4096 * 4096, 4096, 1024);
  transpose_cast_k<<<dim3(16, 64), 256, 0, stream>>>(
      wv, wqkvT + (size_t)5120 * 4096, 4096, 1024);

  // --- fused QKV projection: 256^2 8-phase, 192 blocks (1/CU on 192 CUs) ---
  gemm_qkv256<<<dim3(24, 8), 512, 0, stream>>>(hiddenB, wqkvT, qbuf, kbuf, vT);

  rope_k<<<(2048 * 32 * 64 + 2048 * 8 * 64) / 256, 256, 0, stream>>>(qbuf,
                                                                     kbuf);

  // woT transpose (overwrites dead hiddenB/wqkvT head)
  transpose_cast_k<<<dim3(64, 64), 256, 0, stream>>>(wo, woT, 4096, 4096);

  attn_k<<<dim3(16, 32), 256, 0, stream>>>(qbuf, kbuf, vT, attnb);

  gemm_bt<float, 0><<<dim3(32, 16), 256, 0, stream>>>(
      attnb, woT, out, nullptr, nullptr, 2048, 4096, 4096, 4096);
}

// Round 3
// 448.883 us; speedup vs baseline: 1.0875x; 1.0607x over previous
//
#include <hip/hip_runtime.h>
#include <hip/hip_bf16.h>
#include <math.h>

typedef __bf16 bf16;
typedef __attribute__((ext_vector_type(8))) __bf16 bf16x8;
typedef __attribute__((ext_vector_type(4))) __bf16 bf16x4;
typedef __attribute__((ext_vector_type(4))) float f32x4;

#define MFMA16(a, b, c) __builtin_amdgcn_mfma_f32_16x16x32_bf16(a, b, c, 0, 0, 0)

// async global->LDS, 16B per lane; lds dest must be wave-uniform base
// (HW writes base + lane*16) -- LDS tiles are therefore UNPADDED/linear.
__device__ __forceinline__ void load16_lds(const bf16* g, bf16* l) {
  __builtin_amdgcn_global_load_lds(
      (const __attribute__((address_space(1))) void*)g,
      (__attribute__((address_space(3))) void*)l, 16, 0, 0);
}

// ---------------------------------------------------------------------------
// fp32 -> bf16 cast (hidden_states), 8 elems/thread
// ---------------------------------------------------------------------------
__global__ __launch_bounds__(256) void cast_k(const float* __restrict__ src,
                                              bf16* __restrict__ dst) {
  const size_t i = ((size_t)blockIdx.x * 256 + threadIdx.x) * 8;
  f32x4 a = *(const f32x4*)(src + i);
  f32x4 b = *(const f32x4*)(src + i + 4);
  bf16x8 h;
#pragma unroll
  for (int j = 0; j < 4; ++j) {
    h[j] = (bf16)a[j];
    h[4 + j] = (bf16)b[j];
  }
  *(bf16x8*)(dst + i) = h;
}

// ---------------------------------------------------------------------------
// Transpose + cast: src [rows][cols] fp32 -> dst [cols][rows] bf16.
// ---------------------------------------------------------------------------
__global__ __launch_bounds__(256) void transpose_cast_k(
    const float* __restrict__ src, bf16* __restrict__ dst, int rows,
    int cols) {
  __shared__ float tile[64][65];
  const int c0 = blockIdx.x * 64, r0 = blockIdx.y * 64;
  const int tid = threadIdx.x;
  const int lr = tid >> 4;          // 0..15
  const int lc = (tid & 15) * 4;    // 0..60
#pragma unroll
  for (int i = 0; i < 4; ++i) {
    const int row = lr + i * 16;
    const f32x4 v = *(const f32x4*)&src[(size_t)(r0 + row) * cols + c0 + lc];
#pragma unroll
    for (int j = 0; j < 4; ++j) tile[row][lc + j] = v[j];
  }
  __syncthreads();
#pragma unroll
  for (int i = 0; i < 4; ++i) {
    const int orow = lr + i * 16;  // = src col index within tile
    bf16x4 h;
#pragma unroll
    for (int j = 0; j < 4; ++j) h[j] = (bf16)tile[lc + j][orow];
    *(bf16x4*)&dst[(size_t)(c0 + orow) * rows + r0 + lc] = h;
  }
}

// ---------------------------------------------------------------------------
// 256 x (64*NFRAG) 8-phase GEMM, generalized m201 template.
// C = A[M x K] @ Bt[N x K]^T, bf16 in, fp32 acc.
// Grid must be (N/BN, M/256); BOTH uses here give exactly 256 blocks = 1/CU.
//   QKV:  NFRAG=3 (BN=192), grid (32,8): N=6144 fused [q 4096|k 1024|v 1024]
//   OUT:  NFRAG=2 (BN=128), grid (32,8): N=4096, plain fp32 C (ldc)
//
// 512 thr = 8 waves (2M x 4N); per-wave output 128 x 16*NFRAG.
// LDS: As[2][256*64] + Bs[2][BN*64] linear (112 / 96 KiB), dbuf.
// Swizzle: read elem-off ^= (row&7)<<3; staging pre-swizzles the GLOBAL
// source chunk (c ^ row&7) so global_load_lds dest stays linear (both-sides).
//
// Phase skeleton per iteration (2 K-tiles, t0->buf0, t1->buf1), unchanged
// from the verified round-2 kernel; only the B-half split generalizes to
// {BH0,BH1} = {2,1} (NFRAG=3) or {1,1} (NFRAG=2):
//   ph1: dsA(half0)+dsB(half0) | bar | lgkm0 | MFMA | bar
//   ph2: dsB(half1)            | bar | lgkm0 | MFMA | bar
//   ph3: dsA(half1)+STAGE_B    | bar | lgkm0 | MFMA | bar
//   ph4: STAGE_A + vmcnt(NFRAG+4) | bar | MFMA | bar      (no ds_read here)
//   ph5..8: same on buf1.
// Stages only touch regions whose last reader closed a barrier earlier in
// the same iteration; vmcnt(NFRAG+4) = other-buffer loads all landed with
// 3 half-tiles still in flight. Never vmcnt(0) in the loop.
// ---------------------------------------------------------------------------
#define BARX() __builtin_amdgcn_s_barrier()
#define LGKM0() asm volatile("s_waitcnt lgkmcnt(0)" ::: "memory")
#define VMC7() asm volatile("s_waitcnt vmcnt(7)" ::: "memory")
#define VMC6() asm volatile("s_waitcnt vmcnt(6)" ::: "memory")
#define VMC0() asm volatile("s_waitcnt vmcnt(0)" ::: "memory")

#define DS_A(BUF, QM)                                                       \
  {                                                                         \
    _Pragma("unroll") for (int mi = 0; mi < 4; ++mi)                        \
        _Pragma("unroll") for (int kk = 0; kk < 2; ++kk)                    \
            a[mi][kk] = *(const bf16x8*)&As[BUF][(aBase ^ (kk << 5)) +      \
                                                (QM)*4096 + mi * 1024];     \
  }

#define DS_B(BUF, NOFF, BR, NH)                                             \
  {                                                                         \
    _Pragma("unroll") for (int ni = 0; ni < (NH); ++ni)                     \
        _Pragma("unroll") for (int kk = 0; kk < 2; ++kk)                    \
            BR[ni][kk] = *(const bf16x8*)&Bs[BUF][(bBase ^ (kk << 5)) +     \
                                                  ((NOFF) + ni) * 1024];    \
  }

#define MMAC(QM, NOFF, BR, NH)                                              \
  {                                                                         \
    __builtin_amdgcn_s_setprio(1);                                          \
    _Pragma("unroll") for (int mi = 0; mi < 4; ++mi)                        \
        _Pragma("unroll") for (int ni = 0; ni < (NH); ++ni) {               \
      acc[(QM)*4 + mi][(NOFF) + ni] =                                       \
          MFMA16(a[mi][0], BR[ni][0], acc[(QM)*4 + mi][(NOFF) + ni]);       \
      acc[(QM)*4 + mi][(NOFF) + ni] =                                       \
          MFMA16(a[mi][1], BR[ni][1], acc[(QM)*4 + mi][(NOFF) + ni]);       \
    }                                                                       \
    __builtin_amdgcn_s_setprio(0);                                          \
  }

#define STAGE_A(BUF, T)                                                     \
  {                                                                         \
    const bf16* g0 = aS0 + (size_t)(T)*64;                                  \
    const bf16* g1 = aS1 + (size_t)(T)*64;                                  \
    bf16* l = &As[BUF][w * 512];                                            \
    load16_lds(g0, l);                                                      \
    load16_lds(g1, l + 4096);                                               \
    load16_lds(g0 + ROWK128, l + 8192);                                     \
    load16_lds(g1 + ROWK128, l + 12288);                                    \
  }

#define STAGE_B(BUF, T)                                                     \
  {                                                                         \
    _Pragma("unroll") for (int j = 0; j < NFRAG; ++j)                       \
        load16_lds(bS0 + (size_t)(T)*64 + (size_t)j * 64 * K,               \
                   &Bs[BUF][j * 4096 + w * 512]);                           \
  }

template <typename OT, int NFRAG, int EPI>
__global__ __launch_bounds__(512, 2) void gemm256(
    const bf16* __restrict__ A, const bf16* __restrict__ Bt,
    OT* __restrict__ C, bf16* __restrict__ Ck, bf16* __restrict__ Cv, int K,
    int ldc) {
  constexpr int BN = NFRAG * 64;
  constexpr int BH0 = (NFRAG + 1) / 2;  // 3 -> {2,1}; 2 -> {1,1}
  constexpr int BH1 = NFRAG - BH0;
  const size_t ROWK128 = (size_t)128 * K;
  __shared__ bf16 As[2][256 * 64];
  __shared__ bf16 Bs[2][BN * 64];

  const int tid = threadIdx.x;
  const int lane = tid & 63;
  const int w = tid >> 6;   // 0..7
  const int wm = w >> 2;    // 0..1
  const int wn = w & 3;     // 0..3
  const int quad = lane >> 4;
  const int m16 = lane & 15;

  const int rowBase = blockIdx.y * 256;
  const int colBase = blockIdx.x * BN;

  // staging source map (pre-swizzled): chunk u -> row=u>>3, src chunk
  // (u&7)^(row&7). B rows beyond 64 come from +j*64 (row&7 invariant).
  const int u0 = tid, u1 = 512 + tid;
  const int r0 = u0 >> 3, c0s = (u0 & 7) ^ (r0 & 7);
  const int r1 = u1 >> 3, c1s = (u1 & 7) ^ (r1 & 7);
  const bf16* aS0 = A + (size_t)(rowBase + r0) * K + c0s * 8;
  const bf16* aS1 = A + (size_t)(rowBase + r1) * K + c1s * 8;
  const bf16* bS0 = Bt + (size_t)(colBase + r0) * K + c0s * 8;

  // read-side swizzled bases: row&7 == m16&7 for every fragment row
  const int xsw = (m16 & 7) << 3;
  const int ko0 = (quad * 8) ^ xsw;
  const int aBase = (wm * 128 + m16) * 64 + ko0;
  const int bBase = (wn * (16 * NFRAG) + m16) * 64 + ko0;

  f32x4 acc[8][NFRAG];
#pragma unroll
  for (int i = 0; i < 8; ++i)
#pragma unroll
    for (int j = 0; j < NFRAG; ++j) acc[i][j] = (f32x4){0.f, 0.f, 0.f, 0.f};

  bf16x8 a[4][2], b0[BH0][2], b1[BH1 > 0 ? BH1 : 1][2];

  // prologue: tile0 -> buf0, tile1 -> buf1
  STAGE_A(0, 0);
  STAGE_B(0, 0);
  STAGE_A(1, 1);
  STAGE_B(1, 1);
  if constexpr (NFRAG == 3) VMC7(); else VMC6();  // tile0 fully landed
  BARX();

  const int nT = K / 64;
#pragma unroll 1
  for (int i = 0; i < nT / 2; ++i) {
    const int p0 = (2 * i + 2 < nT) ? 2 * i + 2 : 0;  // clamp: data unused
    const int p1 = (2 * i + 3 < nT) ? 2 * i + 3 : 0;
    // ---- phase 1 ----
    DS_A(0, 0);
    DS_B(0, 0, b0, BH0);
    BARX();
    LGKM0();
    MMAC(0, 0, b0, BH0);
    BARX();
    // ---- phase 2 ----
    DS_B(0, BH0, b1, BH1);
    BARX();
    LGKM0();
    MMAC(0, BH0, b1, BH1);
    BARX();
    // ---- phase 3 ----
    DS_A(0, 1);
    STAGE_B(0, p0);
    BARX();
    LGKM0();
    MMAC(1, 0, b0, BH0);
    BARX();
    // ---- phase 4 ----
    STAGE_A(0, p0);
    if constexpr (NFRAG == 3) VMC7(); else VMC6();
    BARX();
    MMAC(1, BH0, b1, BH1);
    BARX();
    // ---- phase 5 ----
    DS_A(1, 0);
    DS_B(1, 0, b0, BH0);
    BARX();
    LGKM0();
    MMAC(0, 0, b0, BH0);
    BARX();
    // ---- phase 6 ----
    DS_B(1, BH0, b1, BH1);
    BARX();
    LGKM0();
    MMAC(0, BH0, b1, BH1);
    BARX();
    // ---- phase 7 ----
    DS_A(1, 1);
    STAGE_B(1, p1);
    BARX();
    LGKM0();
    MMAC(1, 0, b0, BH0);
    BARX();
    // ---- phase 8 ----
    STAGE_A(1, p1);
    if constexpr (NFRAG == 3) VMC7(); else VMC6();
    BARX();
    MMAC(1, BH0, b1, BH1);
    BARX();
  }
  VMC0();  // drain tail prefetches before epilogue

  // epilogue: C/D layout col = lane&15, row = quad*4 + reg
#pragma unroll
  for (int am = 0; am < 8; ++am) {
    const int gr0 = rowBase + wm * 128 + am * 16 + quad * 4;
#pragma unroll
    for (int an = 0; an < NFRAG; ++an) {
      const int base16 = colBase + wn * (16 * NFRAG) + an * 16;
      const int gc = base16 + m16;
      if constexpr (EPI == 0) {
#pragma unroll
        for (int r = 0; r < 4; ++r)
          C[(size_t)(gr0 + r) * ldc + gc] = (OT)acc[am][an][r];
      } else {
        // fragment (16 cols) lies wholly in one region: boundaries 16-aligned
        if (base16 < 4096) {  // Q -> qbuf [2048][4096]
#pragma unroll
          for (int r = 0; r < 4; ++r)
            C[(size_t)(gr0 + r) * 4096 + gc] = (OT)acc[am][an][r];
        } else if (base16 < 5120) {  // K -> kbuf [2048][1024]
#pragma unroll
          for (int r = 0; r < 4; ++r)
            Ck[(size_t)(gr0 + r) * 1024 + (gc - 4096)] = (bf16)acc[am][an][r];
        } else {  // V -> vT [1024][2048]
          bf16x4 h;
#pragma unroll
          for (int r = 0; r < 4; ++r) h[r] = (bf16)acc[am][an][r];
          *(bf16x4*)&Cv[(size_t)(gc - 5120) * 2048 + gr0] = h;
        }
      }
    }
  }
}

// ---------------------------------------------------------------------------
// RoPE (rotate-half, in place). Fast transcendentals.
// ---------------------------------------------------------------------------
__global__ __launch_bounds__(256) void rope_k(bf16* __restrict__ qb,
                                              bf16* __restrict__ kb) {
  const int NQTOT = 2048 * 32 * 64;
  const int NKTOT = 2048 * 8 * 64;
  int idx = blockIdx.x * 256 + threadIdx.x;
  bf16* buf;
  int nh, rest;
  if (idx < NQTOT) {
    buf = qb;
    nh = 32;
    rest = idx;
  } else {
    rest = idx - NQTOT;
    if (rest >= NKTOT) return;
    buf = kb;
    nh = 8;
  }
  const int j = rest & 63;
  const int hs = rest >> 6;
  const int hh = hs % nh;
  const int s = hs / nh;
  // 10000^(-j/64) = exp(-j * ln(10000)/64)
  const float inv = __expf((float)j * -0.14391157f);
  const float f = (float)s * inv;
  float sn, cs;
  __sincosf(f, &sn, &cs);
  const size_t base = (size_t)(s * nh + hh) * 128 + j;
  const float x1 = (float)buf[base];
  const float x2 = (float)buf[base + 64];
  buf[base] = (bf16)(x1 * cs - x2 * sn);
  buf[base + 64] = (bf16)(x2 * cs + x1 * sn);
}

// ---------------------------------------------------------------------------
// Flash attention, streaming (sink + local) mask — unchanged this round.
// ---------------------------------------------------------------------------
__global__ __launch_bounds__(256, 2) void attn_k(const bf16* __restrict__ q,
                                                 const bf16* __restrict__ kbuf,
                                                 const bf16* __restrict__ vT,
                                                 bf16* __restrict__ attn) {
  const int qb = 15 - blockIdx.x;
  const int h = blockIdx.y;
  const int kvh = h >> 2;
  const int tid = threadIdx.x;
  const int lane = tid & 63;
  const int w = tid >> 6;
  const int quad = lane >> 4;
  const int m16 = lane & 15;

  __shared__ bf16 Ks[4][64 * 32];
  __shared__ bf16 Vs[2][128 * 32];
  __shared__ bf16 Ps[128][72];

  const int qrow0 = qb * 128 + w * 32;

  bf16x8 qf[2][4];
#pragma unroll
  for (int rt = 0; rt < 2; ++rt)
#pragma unroll
    for (int kt = 0; kt < 4; ++kt)
      qf[rt][kt] = *(const bf16x8*)&q[(size_t)(qrow0 + rt * 16 + m16) * 4096 +
                                      h * 128 + kt * 32 + quad * 8];

  f32x4 o[2][8];
  float lsum[2][4];
#pragma unroll
  for (int rt = 0; rt < 2; ++rt) {
#pragma unroll
    for (int dt = 0; dt < 8; ++dt) o[rt][dt] = (f32x4){0.f, 0.f, 0.f, 0.f};
#pragma unroll
    for (int r = 0; r < 4; ++r) lsum[rt][r] = 0.f;
  }

  const float scale = 0.08838834764831845f;  // 1/sqrt(128)
  const bf16* kbase = kbuf + kvh * 128;
  const bf16* vbase = vT + (size_t)(kvh * 128) * 2048;

  const int klocal = (lane >> 2);
  const int kseg = (lane & 3) * 8;

  for (int b = 0; b <= qb; ++b) {
    if (b > 0 && (qb - b) >= 8) continue;  // streaming mask: sink or local
    const bool diag = (b == qb);
    for (int half = 0; half < 2; ++half) {
      const int gk0 = b * 128 + half * 64;

#pragma unroll
      for (int i = 0; i < 4; ++i) {
        const int j = w * 4 + i;
        const int kt = j >> 2, grp = (j & 3) * 16;
        load16_lds(kbase + (size_t)(gk0 + grp + klocal) * 1024 + kt * 32 + kseg,
                   &Ks[kt][grp * 32]);
      }
#pragma unroll
      for (int i = 0; i < 4; ++i) {
        const int j = w * 4 + i;
        const int kc = j >> 3, grp = (j & 7) * 16;
        load16_lds(vbase + (size_t)(grp + klocal) * 2048 + gk0 + kc * 32 + kseg,
                   &Vs[kc][grp * 32]);
      }
      __syncthreads();

      const bool skip = diag && (half * 64 > w * 32 + 31);
      if (!skip) {
        f32x4 sc[2][4];
#pragma unroll
        for (int rt = 0; rt < 2; ++rt)
#pragma unroll
          for (int ct = 0; ct < 4; ++ct)
            sc[rt][ct] = (f32x4){0.f, 0.f, 0.f, 0.f};
#pragma unroll
        for (int kt = 0; kt < 4; ++kt) {
          bf16x8 kf[4];
#pragma unroll
          for (int ct = 0; ct < 4; ++ct)
            kf[ct] = *(const bf16x8*)&Ks[kt][(ct * 16 + m16) * 32 + quad * 8];
#pragma unroll
          for (int rt = 0; rt < 2; ++rt)
#pragma unroll
            for (int ct = 0; ct < 4; ++ct)
              sc[rt][ct] = MFMA16(qf[rt][kt], kf[ct], sc[rt][ct]);
        }

#pragma unroll
        for (int rt = 0; rt < 2; ++rt)
#pragma unroll
          for (int ct = 0; ct < 4; ++ct)
#pragma unroll
            for (int r = 0; r < 4; ++r) {
              float p = __expf(sc[rt][ct][r] * scale);
              if (diag) {
                const int colg = gk0 + ct * 16 + m16;
                const int rowg = qrow0 + rt * 16 + quad * 4 + r;
                if (colg > rowg) p = 0.f;
              }
              lsum[rt][r] += p;
              Ps[w * 32 + rt * 16 + quad * 4 + r][ct * 16 + m16] = (bf16)p;
            }

#pragma unroll
        for (int rt = 0; rt < 2; ++rt)
#pragma unroll
          for (int kc = 0; kc < 2; ++kc) {
            const bf16x8 pa =
                *(const bf16x8*)&Ps[w * 32 + rt * 16 + m16][kc * 32 + quad * 8];
#pragma unroll
            for (int dt = 0; dt < 8; ++dt) {
              const bf16x8 vb =
                  *(const bf16x8*)&Vs[kc][(dt * 16 + m16) * 32 + quad * 8];
              o[rt][dt] = MFMA16(pa, vb, o[rt][dt]);
            }
          }
      }
      __syncthreads();
    }
  }

#pragma unroll
  for (int rt = 0; rt < 2; ++rt) {
    float inv[4];
#pragma unroll
    for (int r = 0; r < 4; ++r) {
      float s = lsum[rt][r];
      s += __shfl_xor(s, 1);
      s += __shfl_xor(s, 2);
      s += __shfl_xor(s, 4);
      s += __shfl_xor(s, 8);
      inv[r] = 1.0f / s;
    }
#pragma unroll
    for (int dt = 0; dt < 8; ++dt)
#pragma unroll
      for (int r = 0; r < 4; ++r)
        attn[(size_t)(qrow0 + rt * 16 + quad * 4 + r) * 4096 + h * 128 +
             dt * 16 + m16] = (bf16)(o[rt][dt][r] * inv[r]);
  }
}

// ---------------------------------------------------------------------------
// Workspace layout (88 MB; aliasing is stream-order safe):
//   off   0 MB: hiddenB (16MB)            -- dead after QKV gemm
//   off  16 MB: wqkvT  (48MB = q|k|v)     -- dead after QKV gemm
//       woT (32MB) later at off 0  (overwrites hiddenB + wqkvT head)
//       attnb (16MB) later at off 32 (overwrites wqkvT middle)
//   off  64 MB: qbuf (16MB)
//   off  80 MB: kbuf (4MB)
//   off  84 MB: vT  (4MB)
// ---------------------------------------------------------------------------
extern "C" void kernel_launch(void* const* d_in, const int* in_sizes, int n_in,
                              void* d_out, int out_size, void* d_ws,
                              size_t ws_size, hipStream_t stream) {
  const float* hidden = (const float*)d_in[0];
  const float* wq = (const float*)d_in[1];
  const float* wk = (const float*)d_in[2];
  const float* wv = (const float*)d_in[3];
  const float* wo = (const float*)d_in[4];
  float* out = (float*)d_out;

  const size_t MB = 1024 * 1024;
  bf16* hiddenB = (bf16*)d_ws;
  bf16* wqkvT = (bf16*)((char*)d_ws + 16 * MB);
  bf16* woT = (bf16*)d_ws;
  bf16* attnb = (bf16*)((char*)d_ws + 32 * MB);
  bf16* qbuf = (bf16*)((char*)d_ws + 64 * MB);
  bf16* kbuf = (bf16*)((char*)d_ws + 80 * MB);
  bf16* vT = (bf16*)((char*)d_ws + 84 * MB);

  // --- one-time casts/transposes ---
  cast_k<<<4096, 256, 0, stream>>>(hidden, hiddenB);
  transpose_cast_k<<<dim3(64, 64), 256, 0, stream>>>(wq, wqkvT, 4096, 4096);
  transpose_cast_k<<<dim3(16, 64), 256, 0, stream>>>(
      wk, wqkvT + (size_t)4096 * 4096, 4096, 1024);
  transpose_cast_k<<<dim3(16, 64), 256, 0, stream>>>(
      wv, wqkvT + (size_t)5120 * 4096, 4096, 1024);

  // --- fused QKV projection: BN=192, grid (32,8) = 256 blocks = 1/CU ---
  gemm256<bf16, 3, 2><<<dim3(32, 8), 512, 0, stream>>>(hiddenB, wqkvT, qbuf,
                                                       kbuf, vT, 4096, 4096);

  rope_k<<<(2048 * 32 * 64 + 2048 * 8 * 64) / 256, 256, 0, stream>>>(qbuf,
                                                                     kbuf);

  // woT transpose (overwrites dead hiddenB/wqkvT head)
  transpose_cast_k<<<dim3(64, 64), 256, 0, stream>>>(wo, woT, 4096, 4096);

  attn_k<<<dim3(16, 32), 256, 0, stream>>>(qbuf, kbuf, vT, attnb);

  // --- output projection: BN=128, grid (32,8) = 256 blocks = 1/CU ---
  gemm256<float, 2, 0><<<dim3(32, 8), 512, 0, stream>>>(
      attnb, woT, out, nullptr, nullptr, 4096, 4096);
}

// Round 4
// 436.627 us; speedup vs baseline: 1.1180x; 1.0281x over previous
//
#include <hip/hip_runtime.h>
#include <hip/hip_bf16.h>
#include <math.h>

typedef __bf16 bf16;
typedef __attribute__((ext_vector_type(8))) __bf16 bf16x8;
typedef __attribute__((ext_vector_type(4))) __bf16 bf16x4;
typedef __attribute__((ext_vector_type(4))) float f32x4;

#define MFMA16(a, b, c) __builtin_amdgcn_mfma_f32_16x16x32_bf16(a, b, c, 0, 0, 0)

// async global->LDS, 16B per lane; lds dest must be wave-uniform base
// (HW writes base + lane*16) -- LDS tiles are therefore UNPADDED/linear.
__device__ __forceinline__ void load16_lds(const bf16* g, bf16* l) {
  __builtin_amdgcn_global_load_lds(
      (const __attribute__((address_space(1))) void*)g,
      (__attribute__((address_space(3))) void*)l, 16, 0, 0);
}

// ---------------------------------------------------------------------------
// fp32 -> bf16 cast (hidden_states), 8 elems/thread
// ---------------------------------------------------------------------------
__global__ __launch_bounds__(256) void cast_k(const float* __restrict__ src,
                                              bf16* __restrict__ dst) {
  const size_t i = ((size_t)blockIdx.x * 256 + threadIdx.x) * 8;
  f32x4 a = *(const f32x4*)(src + i);
  f32x4 b = *(const f32x4*)(src + i + 4);
  bf16x8 h;
#pragma unroll
  for (int j = 0; j < 4; ++j) {
    h[j] = (bf16)a[j];
    h[4 + j] = (bf16)b[j];
  }
  *(bf16x8*)(dst + i) = h;
}

// ---------------------------------------------------------------------------
// Transpose + cast: src [rows][cols] fp32 -> dst [cols][rows] bf16.
// ---------------------------------------------------------------------------
__global__ __launch_bounds__(256) void transpose_cast_k(
    const float* __restrict__ src, bf16* __restrict__ dst, int rows,
    int cols) {
  __shared__ float tile[64][65];
  const int c0 = blockIdx.x * 64, r0 = blockIdx.y * 64;
  const int tid = threadIdx.x;
  const int lr = tid >> 4;          // 0..15
  const int lc = (tid & 15) * 4;    // 0..60
#pragma unroll
  for (int i = 0; i < 4; ++i) {
    const int row = lr + i * 16;
    const f32x4 v = *(const f32x4*)&src[(size_t)(r0 + row) * cols + c0 + lc];
#pragma unroll
    for (int j = 0; j < 4; ++j) tile[row][lc + j] = v[j];
  }
  __syncthreads();
#pragma unroll
  for (int i = 0; i < 4; ++i) {
    const int orow = lr + i * 16;  // = src col index within tile
    bf16x4 h;
#pragma unroll
    for (int j = 0; j < 4; ++j) h[j] = (bf16)tile[lc + j][orow];
    *(bf16x4*)&dst[(size_t)(c0 + orow) * rows + r0 + lc] = h;
  }
}

// ---------------------------------------------------------------------------
// 256 x (64*NFRAG) GEMM, 4 fat phases / iteration, ONE barrier per phase.
// C = A[M x K] @ Bt[N x K]^T, bf16 in, fp32 acc. Grid (N/BN, M/256) = 256
// blocks = 1/CU for both uses:
//   QKV:  NFRAG=3 (BN=192), grid (32,8): N=6144 fused [q 4096|k 1024|v 1024]
//   OUT:  NFRAG=2 (BN=128), grid (32,8): N=4096, plain fp32 C (ldc)
//
// WHY 4x1-barrier phases: rounds 0/2/3 showed ~256 sync intervals/block all
// cost ~1150 cyc regardless of interior work (124 us invariant). So: fewer,
// fatter intervals. Per phase: one qm-half x ALL N frags (24/16 MFMA).
//
// Safety of single barrier: each wave does lgkmcnt(0) BEFORE its barrier, so
// all phase-p LDS reads complete before any wave issues a phase-p+1 stage.
// Stage slots (iter j, buf0=tile 2j, buf1=2j+1):
//   ph1: stage A(2j+1)->buf1.A  (last read ph4(j-1), barrier-ordered)
//   ph2: stage B(2j+2)->buf0.B  (last read ph1)
//   ph3: stage A(2j+2)->buf0.A  (last read ph2)
//   ph4: stage B(2j+3)->buf1.B  (last read ph3)
// Gates (vmcnt counts per-wave VMEM FIFO):
//   end ph2: outstanding = B(2j+1)[N] A(2j+1)[4] B(2j+2)[N] -> vmcnt(N)
//            drains buf1's tile before ph3 reads it.
//   end ph4: outstanding = B(2j+2)[N] A(2j+2)[4] B(2j+3)[N] -> vmcnt(N)
//            drains buf0's next tile before ph1(j+1) reads it.
// Prefetch distance >= 2 fat phases (~2400 cyc) > HBM latency (~900).
// Swizzle (unchanged, conflict-free per round-2 PMC): read elem ^= (row&7)<<3;
// staging pre-swizzles the GLOBAL source chunk so LDS dest stays linear.
// ---------------------------------------------------------------------------
#define BARX() __builtin_amdgcn_s_barrier()
#define LGKM0() asm volatile("s_waitcnt lgkmcnt(0)" ::: "memory")
#define VMC0() asm volatile("s_waitcnt vmcnt(0)" ::: "memory")
#define VMCN()                                           \
  {                                                      \
    if constexpr (NFRAG == 3) {                          \
      asm volatile("s_waitcnt vmcnt(3)" ::: "memory");   \
    } else {                                             \
      asm volatile("s_waitcnt vmcnt(2)" ::: "memory");   \
    }                                                    \
  }

#define DS_A(BUF, QM)                                                       \
  {                                                                         \
    _Pragma("unroll") for (int mi = 0; mi < 4; ++mi)                        \
        _Pragma("unroll") for (int kk = 0; kk < 2; ++kk)                    \
            a[mi][kk] = *(const bf16x8*)&As[BUF][(aBase ^ (kk << 5)) +      \
                                                (QM)*4096 + mi * 1024];     \
  }

#define DS_B(BUF)                                                           \
  {                                                                         \
    _Pragma("unroll") for (int ni = 0; ni < NFRAG; ++ni)                    \
        _Pragma("unroll") for (int kk = 0; kk < 2; ++kk)                    \
            b[ni][kk] = *(const bf16x8*)&Bs[BUF][(bBase ^ (kk << 5)) +      \
                                                 ni * 1024];                \
  }

#define MMAC(QM)                                                            \
  {                                                                         \
    __builtin_amdgcn_s_setprio(1);                                          \
    _Pragma("unroll") for (int mi = 0; mi < 4; ++mi)                        \
        _Pragma("unroll") for (int ni = 0; ni < NFRAG; ++ni) {              \
      acc[(QM)*4 + mi][ni] = MFMA16(a[mi][0], b[ni][0], acc[(QM)*4 + mi][ni]); \
      acc[(QM)*4 + mi][ni] = MFMA16(a[mi][1], b[ni][1], acc[(QM)*4 + mi][ni]); \
    }                                                                       \
    __builtin_amdgcn_s_setprio(0);                                          \
  }

#define STAGE_A(BUF, T)                                                     \
  {                                                                         \
    const bf16* g0 = aS0 + (size_t)(T)*64;                                  \
    const bf16* g1 = aS1 + (size_t)(T)*64;                                  \
    bf16* l = &As[BUF][w * 512];                                            \
    load16_lds(g0, l);                                                      \
    load16_lds(g1, l + 4096);                                               \
    load16_lds(g0 + ROWK128, l + 8192);                                     \
    load16_lds(g1 + ROWK128, l + 12288);                                    \
  }

#define STAGE_B(BUF, T)                                                     \
  {                                                                         \
    _Pragma("unroll") for (int jj = 0; jj < NFRAG; ++jj)                    \
        load16_lds(bS0 + (size_t)(T)*64 + (size_t)jj * 64 * K,              \
                   &Bs[BUF][jj * 4096 + w * 512]);                          \
  }

template <typename OT, int NFRAG, int EPI>
__global__ __launch_bounds__(512, 2) void gemm256(
    const bf16* __restrict__ A, const bf16* __restrict__ Bt,
    OT* __restrict__ C, bf16* __restrict__ Ck, bf16* __restrict__ Cv, int K,
    int ldc) {
  constexpr int BN = NFRAG * 64;
  const size_t ROWK128 = (size_t)128 * K;
  __shared__ bf16 As[2][256 * 64];
  __shared__ bf16 Bs[2][BN * 64];

  const int tid = threadIdx.x;
  const int lane = tid & 63;
  const int w = tid >> 6;   // 0..7
  const int wm = w >> 2;    // 0..1
  const int wn = w & 3;     // 0..3
  const int quad = lane >> 4;
  const int m16 = lane & 15;

  const int rowBase = blockIdx.y * 256;
  const int colBase = blockIdx.x * BN;

  // staging source map (pre-swizzled): chunk u -> row=u>>3, src chunk
  // (u&7)^(row&7). B rows beyond 64 come from +j*64 (row&7 invariant).
  const int u0 = tid, u1 = 512 + tid;
  const int r0 = u0 >> 3, c0s = (u0 & 7) ^ (r0 & 7);
  const int r1 = u1 >> 3, c1s = (u1 & 7) ^ (r1 & 7);
  const bf16* aS0 = A + (size_t)(rowBase + r0) * K + c0s * 8;
  const bf16* aS1 = A + (size_t)(rowBase + r1) * K + c1s * 8;
  const bf16* bS0 = Bt + (size_t)(colBase + r0) * K + c0s * 8;

  // read-side swizzled bases: row&7 == m16&7 for every fragment row
  const int xsw = (m16 & 7) << 3;
  const int ko0 = (quad * 8) ^ xsw;
  const int aBase = (wm * 128 + m16) * 64 + ko0;
  const int bBase = (wn * (16 * NFRAG) + m16) * 64 + ko0;

  f32x4 acc[8][NFRAG];
#pragma unroll
  for (int i = 0; i < 8; ++i)
#pragma unroll
    for (int j = 0; j < NFRAG; ++j) acc[i][j] = (f32x4){0.f, 0.f, 0.f, 0.f};

  bf16x8 a[4][2], b[NFRAG][2];

  // prologue: FIFO order B(0)[N], A(0)[4], B(1)[N]; vmcnt(N) drains B0+A0.
  STAGE_B(0, 0);
  STAGE_A(0, 0);
  STAGE_B(1, 1);
  VMCN();
  BARX();

  const int nT = K / 64;
#pragma unroll 1
  for (int j = 0; j < nT / 2; ++j) {
    const int pO1 = 2 * j + 1;                         // odd tile A (this iter)
    const int pE = (2 * j + 2 < nT) ? 2 * j + 2 : 0;   // clamp: data unused
    const int pO2 = (2 * j + 3 < nT) ? 2 * j + 3 : 0;  // clamp: data unused
    // ---- ph1: buf0 / qm0, all N ----
    DS_B(0);
    DS_A(0, 0);
    STAGE_A(1, pO1);
    LGKM0();
    MMAC(0);
    BARX();
    // ---- ph2: buf0 / qm1 ----
    DS_A(0, 1);
    STAGE_B(0, pE);
    VMCN();  // buf1 (tile 2j+1) fully landed before ph3 reads it
    LGKM0();
    MMAC(1);
    BARX();
    // ---- ph3: buf1 / qm0, all N ----
    DS_B(1);
    DS_A(1, 0);
    STAGE_A(0, pE);
    LGKM0();
    MMAC(0);
    BARX();
    // ---- ph4: buf1 / qm1 ----
    DS_A(1, 1);
    STAGE_B(1, pO2);
    VMCN();  // buf0 (tile 2j+2) fully landed before next ph1 reads it
    LGKM0();
    MMAC(1);
    BARX();
  }
  VMC0();  // drain tail prefetches before epilogue

  // epilogue: C/D layout col = lane&15, row = quad*4 + reg
#pragma unroll
  for (int am = 0; am < 8; ++am) {
    const int gr0 = rowBase + wm * 128 + am * 16 + quad * 4;
#pragma unroll
    for (int an = 0; an < NFRAG; ++an) {
      const int base16 = colBase + wn * (16 * NFRAG) + an * 16;
      const int gc = base16 + m16;
      if constexpr (EPI == 0) {
#pragma unroll
        for (int r = 0; r < 4; ++r)
          C[(size_t)(gr0 + r) * ldc + gc] = (OT)acc[am][an][r];
      } else {
        // fragment (16 cols) lies wholly in one region: boundaries 16-aligned
        if (base16 < 4096) {  // Q -> qbuf [2048][4096]
#pragma unroll
          for (int r = 0; r < 4; ++r)
            C[(size_t)(gr0 + r) * 4096 + gc] = (OT)acc[am][an][r];
        } else if (base16 < 5120) {  // K -> kbuf [2048][1024]
#pragma unroll
          for (int r = 0; r < 4; ++r)
            Ck[(size_t)(gr0 + r) * 1024 + (gc - 4096)] = (bf16)acc[am][an][r];
        } else {  // V -> vT [1024][2048]
          bf16x4 h;
#pragma unroll
          for (int r = 0; r < 4; ++r) h[r] = (bf16)acc[am][an][r];
          *(bf16x4*)&Cv[(size_t)(gc - 5120) * 2048 + gr0] = h;
        }
      }
    }
  }
}

// ---------------------------------------------------------------------------
// RoPE (rotate-half, in place). Fast transcendentals.
// ---------------------------------------------------------------------------
__global__ __launch_bounds__(256) void rope_k(bf16* __restrict__ qb,
                                              bf16* __restrict__ kb) {
  const int NQTOT = 2048 * 32 * 64;
  const int NKTOT = 2048 * 8 * 64;
  int idx = blockIdx.x * 256 + threadIdx.x;
  bf16* buf;
  int nh, rest;
  if (idx < NQTOT) {
    buf = qb;
    nh = 32;
    rest = idx;
  } else {
    rest = idx - NQTOT;
    if (rest >= NKTOT) return;
    buf = kb;
    nh = 8;
  }
  const int j = rest & 63;
  const int hs = rest >> 6;
  const int hh = hs % nh;
  const int s = hs / nh;
  // 10000^(-j/64) = exp(-j * ln(10000)/64)
  const float inv = __expf((float)j * -0.14391157f);
  const float f = (float)s * inv;
  float sn, cs;
  __sincosf(f, &sn, &cs);
  const size_t base = (size_t)(s * nh + hh) * 128 + j;
  const float x1 = (float)buf[base];
  const float x2 = (float)buf[base + 64];
  buf[base] = (bf16)(x1 * cs - x2 * sn);
  buf[base + 64] = (bf16)(x2 * cs + x1 * sn);
}

// ---------------------------------------------------------------------------
// Flash attention, streaming (sink + local) mask — unchanged this round.
// ---------------------------------------------------------------------------
__global__ __launch_bounds__(256, 2) void attn_k(const bf16* __restrict__ q,
                                                 const bf16* __restrict__ kbuf,
                                                 const bf16* __restrict__ vT,
                                                 bf16* __restrict__ attn) {
  const int qb = 15 - blockIdx.x;
  const int h = blockIdx.y;
  const int kvh = h >> 2;
  const int tid = threadIdx.x;
  const int lane = tid & 63;
  const int w = tid >> 6;
  const int quad = lane >> 4;
  const int m16 = lane & 15;

  __shared__ bf16 Ks[4][64 * 32];
  __shared__ bf16 Vs[2][128 * 32];
  __shared__ bf16 Ps[128][72];

  const int qrow0 = qb * 128 + w * 32;

  bf16x8 qf[2][4];
#pragma unroll
  for (int rt = 0; rt < 2; ++rt)
#pragma unroll
    for (int kt = 0; kt < 4; ++kt)
      qf[rt][kt] = *(const bf16x8*)&q[(size_t)(qrow0 + rt * 16 + m16) * 4096 +
                                      h * 128 + kt * 32 + quad * 8];

  f32x4 o[2][8];
  float lsum[2][4];
#pragma unroll
  for (int rt = 0; rt < 2; ++rt) {
#pragma unroll
    for (int dt = 0; dt < 8; ++dt) o[rt][dt] = (f32x4){0.f, 0.f, 0.f, 0.f};
#pragma unroll
    for (int r = 0; r < 4; ++r) lsum[rt][r] = 0.f;
  }

  const float scale = 0.08838834764831845f;  // 1/sqrt(128)
  const bf16* kbase = kbuf + kvh * 128;
  const bf16* vbase = vT + (size_t)(kvh * 128) * 2048;

  const int klocal = (lane >> 2);
  const int kseg = (lane & 3) * 8;

  for (int b = 0; b <= qb; ++b) {
    if (b > 0 && (qb - b) >= 8) continue;  // streaming mask: sink or local
    const bool diag = (b == qb);
    for (int half = 0; half < 2; ++half) {
      const int gk0 = b * 128 + half * 64;

#pragma unroll
      for (int i = 0; i < 4; ++i) {
        const int j = w * 4 + i;
        const int kt = j >> 2, grp = (j & 3) * 16;
        load16_lds(kbase + (size_t)(gk0 + grp + klocal) * 1024 + kt * 32 + kseg,
                   &Ks[kt][grp * 32]);
      }
#pragma unroll
      for (int i = 0; i < 4; ++i) {
        const int j = w * 4 + i;
        const int kc = j >> 3, grp = (j & 7) * 16;
        load16_lds(vbase + (size_t)(grp + klocal) * 2048 + gk0 + kc * 32 + kseg,
                   &Vs[kc][grp * 32]);
      }
      __syncthreads();

      const bool skip = diag && (half * 64 > w * 32 + 31);
      if (!skip) {
        f32x4 sc[2][4];
#pragma unroll
        for (int rt = 0; rt < 2; ++rt)
#pragma unroll
          for (int ct = 0; ct < 4; ++ct)
            sc[rt][ct] = (f32x4){0.f, 0.f, 0.f, 0.f};
#pragma unroll
        for (int kt = 0; kt < 4; ++kt) {
          bf16x8 kf[4];
#pragma unroll
          for (int ct = 0; ct < 4; ++ct)
            kf[ct] = *(const bf16x8*)&Ks[kt][(ct * 16 + m16) * 32 + quad * 8];
#pragma unroll
          for (int rt = 0; rt < 2; ++rt)
#pragma unroll
            for (int ct = 0; ct < 4; ++ct)
              sc[rt][ct] = MFMA16(qf[rt][kt], kf[ct], sc[rt][ct]);
        }

#pragma unroll
        for (int rt = 0; rt < 2; ++rt)
#pragma unroll
          for (int ct = 0; ct < 4; ++ct)
#pragma unroll
            for (int r = 0; r < 4; ++r) {
              float p = __expf(sc[rt][ct][r] * scale);
              if (diag) {
                const int colg = gk0 + ct * 16 + m16;
                const int rowg = qrow0 + rt * 16 + quad * 4 + r;
                if (colg > rowg) p = 0.f;
              }
              lsum[rt][r] += p;
              Ps[w * 32 + rt * 16 + quad * 4 + r][ct * 16 + m16] = (bf16)p;
            }

#pragma unroll
        for (int rt = 0; rt < 2; ++rt)
#pragma unroll
          for (int kc = 0; kc < 2; ++kc) {
            const bf16x8 pa =
                *(const bf16x8*)&Ps[w * 32 + rt * 16 + m16][kc * 32 + quad * 8];
#pragma unroll
            for (int dt = 0; dt < 8; ++dt) {
              const bf16x8 vb =
                  *(const bf16x8*)&Vs[kc][(dt * 16 + m16) * 32 + quad * 8];
              o[rt][dt] = MFMA16(pa, vb, o[rt][dt]);
            }
          }
      }
      __syncthreads();
    }
  }

#pragma unroll
  for (int rt = 0; rt < 2; ++rt) {
    float inv[4];
#pragma unroll
    for (int r = 0; r < 4; ++r) {
      float s = lsum[rt][r];
      s += __shfl_xor(s, 1);
      s += __shfl_xor(s, 2);
      s += __shfl_xor(s, 4);
      s += __shfl_xor(s, 8);
      inv[r] = 1.0f / s;
    }
#pragma unroll
    for (int dt = 0; dt < 8; ++dt)
#pragma unroll
      for (int r = 0; r < 4; ++r)
        attn[(size_t)(qrow0 + rt * 16 + quad * 4 + r) * 4096 + h * 128 +
             dt * 16 + m16] = (bf16)(o[rt][dt][r] * inv[r]);
  }
}

// ---------------------------------------------------------------------------
// Workspace layout (88 MB; aliasing is stream-order safe):
//   off   0 MB: hiddenB (16MB)            -- dead after QKV gemm
//   off  16 MB: wqkvT  (48MB = q|k|v)     -- dead after QKV gemm
//       woT (32MB) later at off 0  (overwrites hiddenB + wqkvT head)
//       attnb (16MB) later at off 32 (overwrites wqkvT middle)
//   off  64 MB: qbuf (16MB)
//   off  80 MB: kbuf (4MB)
//   off  84 MB: vT  (4MB)
// ---------------------------------------------------------------------------
extern "C" void kernel_launch(void* const* d_in, const int* in_sizes, int n_in,
                              void* d_out, int out_size, void* d_ws,
                              size_t ws_size, hipStream_t stream) {
  const float* hidden = (const float*)d_in[0];
  const float* wq = (const float*)d_in[1];
  const float* wk = (const float*)d_in[2];
  const float* wv = (const float*)d_in[3];
  const float* wo = (const float*)d_in[4];
  float* out = (float*)d_out;

  const size_t MB = 1024 * 1024;
  bf16* hiddenB = (bf16*)d_ws;
  bf16* wqkvT = (bf16*)((char*)d_ws + 16 * MB);
  bf16* woT = (bf16*)d_ws;
  bf16* attnb = (bf16*)((char*)d_ws + 32 * MB);
  bf16* qbuf = (bf16*)((char*)d_ws + 64 * MB);
  bf16* kbuf = (bf16*)((char*)d_ws + 80 * MB);
  bf16* vT = (bf16*)((char*)d_ws + 84 * MB);

  // --- one-time casts/transposes ---
  cast_k<<<4096, 256, 0, stream>>>(hidden, hiddenB);
  transpose_cast_k<<<dim3(64, 64), 256, 0, stream>>>(wq, wqkvT, 4096, 4096);
  transpose_cast_k<<<dim3(16, 64), 256, 0, stream>>>(
      wk, wqkvT + (size_t)4096 * 4096, 4096, 1024);
  transpose_cast_k<<<dim3(16, 64), 256, 0, stream>>>(
      wv, wqkvT + (size_t)5120 * 4096, 4096, 1024);

  // --- fused QKV projection: BN=192, grid (32,8) = 256 blocks = 1/CU ---
  gemm256<bf16, 3, 2><<<dim3(32, 8), 512, 0, stream>>>(hiddenB, wqkvT, qbuf,
                                                       kbuf, vT, 4096, 4096);

  rope_k<<<(2048 * 32 * 64 + 2048 * 8 * 64) / 256, 256, 0, stream>>>(qbuf,
                                                                     kbuf);

  // woT transpose (overwrites dead hiddenB/wqkvT head)
  transpose_cast_k<<<dim3(64, 64), 256, 0, stream>>>(wo, woT, 4096, 4096);

  attn_k<<<dim3(16, 32), 256, 0, stream>>>(qbuf, kbuf, vT, attnb);

  // --- output projection: BN=128, grid (32,8) = 256 blocks = 1/CU ---
  gemm256<float, 2, 0><<<dim3(32, 8), 512, 0, stream>>>(
      attnb, woT, out, nullptr, nullptr, 4096, 4096);
}

// Round 6
// 422.771 us; speedup vs baseline: 1.1546x; 1.0328x over previous
//
#include <hip/hip_runtime.h>
#include <hip/hip_bf16.h>
#include <math.h>

typedef __bf16 bf16;
typedef __attribute__((ext_vector_type(8))) __bf16 bf16x8;
typedef __attribute__((ext_vector_type(4))) __bf16 bf16x4;
typedef __attribute__((ext_vector_type(4))) float f32x4;

#define MFMA16(a, b, c) __builtin_amdgcn_mfma_f32_16x16x32_bf16(a, b, c, 0, 0, 0)

// async global->LDS, 16B per lane; lds dest must be wave-uniform base
// (HW writes base + lane*16) -- LDS tiles are therefore UNPADDED/linear.
__device__ __forceinline__ void load16_lds(const bf16* g, bf16* l) {
  __builtin_amdgcn_global_load_lds(
      (const __attribute__((address_space(1))) void*)g,
      (__attribute__((address_space(3))) void*)l, 16, 0, 0);
}

// ---------------------------------------------------------------------------
// fp32 -> bf16 cast (hidden_states), 8 elems/thread
// ---------------------------------------------------------------------------
__global__ __launch_bounds__(256) void cast_k(const float* __restrict__ src,
                                              bf16* __restrict__ dst) {
  const size_t i = ((size_t)blockIdx.x * 256 + threadIdx.x) * 8;
  f32x4 a = *(const f32x4*)(src + i);
  f32x4 b = *(const f32x4*)(src + i + 4);
  bf16x8 h;
#pragma unroll
  for (int j = 0; j < 4; ++j) {
    h[j] = (bf16)a[j];
    h[4 + j] = (bf16)b[j];
  }
  *(bf16x8*)(dst + i) = h;
}

// ---------------------------------------------------------------------------
// Transpose + cast: src [rows][cols] fp32 -> dst [cols][rows] bf16.
// ---------------------------------------------------------------------------
__global__ __launch_bounds__(256) void transpose_cast_k(
    const float* __restrict__ src, bf16* __restrict__ dst, int rows,
    int cols) {
  __shared__ float tile[64][65];
  const int c0 = blockIdx.x * 64, r0 = blockIdx.y * 64;
  const int tid = threadIdx.x;
  const int lr = tid >> 4;          // 0..15
  const int lc = (tid & 15) * 4;    // 0..60
#pragma unroll
  for (int i = 0; i < 4; ++i) {
    const int row = lr + i * 16;
    const f32x4 v = *(const f32x4*)&src[(size_t)(r0 + row) * cols + c0 + lc];
#pragma unroll
    for (int j = 0; j < 4; ++j) tile[row][lc + j] = v[j];
  }
  __syncthreads();
#pragma unroll
  for (int i = 0; i < 4; ++i) {
    const int orow = lr + i * 16;  // = src col index within tile
    bf16x4 h;
#pragma unroll
    for (int j = 0; j < 4; ++j) h[j] = (bf16)tile[lc + j][orow];
    *(bf16x4*)&dst[(size_t)(c0 + orow) * rows + r0 + lc] = h;
  }
}

// ---------------------------------------------------------------------------
// 256 x (64*NFRAG) GEMM with EARLY-READ software pipeline.
// C = A[M x K] @ Bt[N x K]^T, bf16 in, fp32 acc. Grid (N/BN, M/256) = 256
// blocks = 1/CU:
//   QKV:  NFRAG=3 (BN=192), grid (32,8): N=6144 fused [q 4096|k 1024|v 1024]
//   OUT:  NFRAG=2 (BN=128), grid (32,8): N=4096, plain fp32 C (ldc)
//
// WHY: rounds 0-4 all measure MfmaUtil 42-45% regardless of barrier count.
// Cause: each phase does {ds_read own frags -> lgkm0 -> MFMA}, serializing
// the LDS pipe (~260 cyc/SIMD) and matrix pipe (~233 cyc). Fix: fragments
// for phase p+1 are ds_read DURING phase p, AFTER p's MFMAs issue -> both
// pipes work concurrently; lgkm0 at phase end catches stragglers.
//
// Per iteration (tiles e=2j in buf0, o=2j+1 in buf1), 4 phases, 1 barrier
// each. Reg sets: bC/bN (B dbuf), a0/a1 (A qm halves). Schedule:
//  ph1: MFMA(bC,a0->qm0 of e) | vmcnt(N+4) | read buf0.A1->a1
//       | stage B,A0(e+2)->buf0 | lgkm0 | bar
//  ph2: MFMA(bC,a1->qm1 of e) | vmcnt(N+4) | read buf1.B->bN, buf1.A0->a0
//       | stage A1(e+2)->buf0 | lgkm0 | bar
//  ph3: MFMA(bN,a0->qm0 of o) | vmcnt(N+4) | read buf1.A1->a1
//       | stage B,A0(o+2)->buf1 | lgkm0 | bar
//  ph4: MFMA(bN,a1->qm1 of o) | vmcnt(N+4) | read buf0.B->bC, buf0.A0->a0
//       | stage A1(o+2)->buf1 | lgkm0 | bar
// Hazard ledger:
//  - stage->region windows: each stage targets a region whose last ds_read
//    was a PRIOR phase (reads run one phase early), barrier-separated; every
//    wave's lgkm0 precedes its barrier, so no wave's stage can land before
//    another wave finished reading old content.
//  - vmcnt gates (FIFO walked for NFRAG=3 and 2): at each gate the drained
//    oldest loads are exactly the regions read in that phase; all stages
//    ride >=3 phases (~1500 cyc) in flight. Never vmcnt(0) in the loop.
//  - no same-phase reg WAR: MFMA reads {bC,a0 / bC,a1 / bN,a0 / bN,a1},
//    ds_reads write {a1 / bN,a0 / a1 / bC,a0}.
// Swizzle unchanged (conflict-free per PMC): read elem ^= (row&7)<<3;
// staging pre-swizzles the GLOBAL source chunk; LDS dest stays linear.
// ---------------------------------------------------------------------------
#define BARX() __builtin_amdgcn_s_barrier()
#define LGKM0() asm volatile("s_waitcnt lgkmcnt(0)" ::: "memory")
#define VMC0() asm volatile("s_waitcnt vmcnt(0)" ::: "memory")
#define VMCN()                                           \
  {                                                      \
    if constexpr (NFRAG == 3) {                          \
      asm volatile("s_waitcnt vmcnt(7)" ::: "memory");   \
    } else {                                             \
      asm volatile("s_waitcnt vmcnt(6)" ::: "memory");   \
    }                                                    \
  }

#define DS_A0(BUF, DST)                                                     \
  {                                                                         \
    _Pragma("unroll") for (int mi = 0; mi < 4; ++mi)                        \
        _Pragma("unroll") for (int kk = 0; kk < 2; ++kk)                    \
            DST[mi][kk] =                                                   \
                *(const bf16x8*)&As[BUF][(aBase ^ (kk << 5)) + mi * 1024];  \
  }

#define DS_A1(BUF, DST)                                                     \
  {                                                                         \
    _Pragma("unroll") for (int mi = 0; mi < 4; ++mi)                        \
        _Pragma("unroll") for (int kk = 0; kk < 2; ++kk)                    \
            DST[mi][kk] = *(const bf16x8*)&As[BUF][(aBase ^ (kk << 5)) +    \
                                                   4096 + mi * 1024];       \
  }

#define DS_B(BUF, DST)                                                      \
  {                                                                         \
    _Pragma("unroll") for (int ni = 0; ni < NFRAG; ++ni)                    \
        _Pragma("unroll") for (int kk = 0; kk < 2; ++kk)                    \
            DST[ni][kk] = *(const bf16x8*)&Bs[BUF][(bBase ^ (kk << 5)) +    \
                                                   ni * 1024];              \
  }

#define MMAC(QM, AR, BR)                                                    \
  {                                                                         \
    __builtin_amdgcn_s_setprio(1);                                          \
    _Pragma("unroll") for (int mi = 0; mi < 4; ++mi)                        \
        _Pragma("unroll") for (int ni = 0; ni < NFRAG; ++ni) {              \
      acc[(QM)*4 + mi][ni] =                                                \
          MFMA16(AR[mi][0], BR[ni][0], acc[(QM)*4 + mi][ni]);               \
      acc[(QM)*4 + mi][ni] =                                                \
          MFMA16(AR[mi][1], BR[ni][1], acc[(QM)*4 + mi][ni]);               \
    }                                                                       \
    __builtin_amdgcn_s_setprio(0);                                          \
  }

// A staging split by qm-region: A0 = rows {0-63,128-191}, A1 = {64-127,192-255}
#define STAGE_A0(BUF, T)                                                    \
  {                                                                         \
    const bf16* g0 = aS0 + (size_t)(T)*64;                                  \
    bf16* l = &As[BUF][w * 512];                                            \
    load16_lds(g0, l);                                                      \
    load16_lds(g0 + ROWK128, l + 8192);                                     \
  }

#define STAGE_A1(BUF, T)                                                    \
  {                                                                         \
    const bf16* g1 = aS1 + (size_t)(T)*64;                                  \
    bf16* l = &As[BUF][w * 512];                                            \
    load16_lds(g1, l + 4096);                                               \
    load16_lds(g1 + ROWK128, l + 12288);                                    \
  }

#define STAGE_B(BUF, T)                                                     \
  {                                                                         \
    _Pragma("unroll") for (int jj = 0; jj < NFRAG; ++jj)                    \
        load16_lds(bS0 + (size_t)(T)*64 + (size_t)jj * 64 * K,              \
                   &Bs[BUF][jj * 4096 + w * 512]);                          \
  }

template <typename OT, int NFRAG, int EPI>
__global__ __launch_bounds__(512, 2) void gemm256(
    const bf16* __restrict__ A, const bf16* __restrict__ Bt,
    OT* __restrict__ C, bf16* __restrict__ Ck, bf16* __restrict__ Cv, int K,
    int ldc) {
  constexpr int BN = NFRAG * 64;
  const size_t ROWK128 = (size_t)128 * K;
  __shared__ bf16 As[2][256 * 64];
  __shared__ bf16 Bs[2][BN * 64];

  const int tid = threadIdx.x;
  const int lane = tid & 63;
  const int w = tid >> 6;   // 0..7
  const int wm = w >> 2;    // 0..1
  const int wn = w & 3;     // 0..3
  const int quad = lane >> 4;
  const int m16 = lane & 15;

  const int rowBase = blockIdx.y * 256;
  const int colBase = blockIdx.x * BN;

  // staging source map (pre-swizzled): chunk u -> row=u>>3, src chunk
  // (u&7)^(row&7). Rows beyond 64 via +64*j offsets (row&7 invariant).
  const int u0 = tid, u1 = 512 + tid;
  const int r0 = u0 >> 3, c0s = (u0 & 7) ^ (r0 & 7);
  const int r1 = u1 >> 3, c1s = (u1 & 7) ^ (r1 & 7);
  const bf16* aS0 = A + (size_t)(rowBase + r0) * K + c0s * 8;
  const bf16* aS1 = A + (size_t)(rowBase + r1) * K + c1s * 8;
  const bf16* bS0 = Bt + (size_t)(colBase + r0) * K + c0s * 8;

  // read-side swizzled bases: row&7 == m16&7 for every fragment row
  const int xsw = (m16 & 7) << 3;
  const int ko0 = (quad * 8) ^ xsw;
  const int aBase = (wm * 128 + m16) * 64 + ko0;
  const int bBase = (wn * (16 * NFRAG) + m16) * 64 + ko0;

  f32x4 acc[8][NFRAG];
#pragma unroll
  for (int i = 0; i < 8; ++i)
#pragma unroll
    for (int j = 0; j < NFRAG; ++j) acc[i][j] = (f32x4){0.f, 0.f, 0.f, 0.f};

  bf16x8 a0[4][2], a1[4][2], bC[NFRAG][2], bN[NFRAG][2];

  // prologue: stage tile0->buf0, tile1->buf1 (FIFO: buf0's N+4 oldest),
  // drain buf0, pre-read ph1's regs; second barrier isolates pre-reads
  // from ph1's stages into buf0 (cross-wave).
  STAGE_B(0, 0);
  STAGE_A0(0, 0);
  STAGE_A1(0, 0);
  STAGE_B(1, 1);
  STAGE_A0(1, 1);
  STAGE_A1(1, 1);
  VMCN();
  BARX();
  DS_B(0, bC);
  DS_A0(0, a0);
  LGKM0();
  BARX();

  const int nT = K / 64;
#pragma unroll 1
  for (int j = 0; j < nT / 2; ++j) {
    const int pe2 = (2 * j + 2 < nT) ? 2 * j + 2 : 0;  // clamp: data unused
    const int po2 = (2 * j + 3 < nT) ? 2 * j + 3 : 0;
    // ---- ph1: compute e/qm0; read A1(e); stage B,A0(e+2)->buf0 ----
    MMAC(0, a0, bC);
    VMCN();
    DS_A1(0, a1);
    STAGE_B(0, pe2);
    STAGE_A0(0, pe2);
    LGKM0();
    BARX();
    // ---- ph2: compute e/qm1; read B(o),A0(o); stage A1(e+2)->buf0 ----
    MMAC(1, a1, bC);
    VMCN();
    DS_B(1, bN);
    DS_A0(1, a0);
    STAGE_A1(0, pe2);
    LGKM0();
    BARX();
    // ---- ph3: compute o/qm0; read A1(o); stage B,A0(o+2)->buf1 ----
    MMAC(0, a0, bN);
    VMCN();
    DS_A1(1, a1);
    STAGE_B(1, po2);
    STAGE_A0(1, po2);
    LGKM0();
    BARX();
    // ---- ph4: compute o/qm1; read B(e+2),A0(e+2); stage A1(o+2)->buf1 ----
    MMAC(1, a1, bN);
    VMCN();
    DS_B(0, bC);
    DS_A0(0, a0);
    STAGE_A1(1, po2);
    LGKM0();
    BARX();
  }
  VMC0();  // drain tail prefetches before epilogue

  // epilogue: C/D layout col = lane&15, row = quad*4 + reg
#pragma unroll
  for (int am = 0; am < 8; ++am) {
    const int gr0 = rowBase + wm * 128 + am * 16 + quad * 4;
#pragma unroll
    for (int an = 0; an < NFRAG; ++an) {
      const int base16 = colBase + wn * (16 * NFRAG) + an * 16;
      const int gc = base16 + m16;
      if constexpr (EPI == 0) {
#pragma unroll
        for (int r = 0; r < 4; ++r)
          C[(size_t)(gr0 + r) * ldc + gc] = (OT)acc[am][an][r];
      } else {
        // fragment (16 cols) lies wholly in one region: boundaries 16-aligned
        if (base16 < 4096) {  // Q -> qbuf [2048][4096]
#pragma unroll
          for (int r = 0; r < 4; ++r)
            C[(size_t)(gr0 + r) * 4096 + gc] = (OT)acc[am][an][r];
        } else if (base16 < 5120) {  // K -> kbuf [2048][1024]
#pragma unroll
          for (int r = 0; r < 4; ++r)
            Ck[(size_t)(gr0 + r) * 1024 + (gc - 4096)] = (bf16)acc[am][an][r];
        } else {  // V -> vT [1024][2048]
          bf16x4 h;
#pragma unroll
          for (int r = 0; r < 4; ++r) h[r] = (bf16)acc[am][an][r];
          *(bf16x4*)&Cv[(size_t)(gc - 5120) * 2048 + gr0] = h;
        }
      }
    }
  }
}

// ---------------------------------------------------------------------------
// RoPE (rotate-half, in place). Fast transcendentals.
// ---------------------------------------------------------------------------
__global__ __launch_bounds__(256) void rope_k(bf16* __restrict__ qb,
                                              bf16* __restrict__ kb) {
  const int NQTOT = 2048 * 32 * 64;
  const int NKTOT = 2048 * 8 * 64;
  int idx = blockIdx.x * 256 + threadIdx.x;
  bf16* buf;
  int nh, rest;
  if (idx < NQTOT) {
    buf = qb;
    nh = 32;
    rest = idx;
  } else {
    rest = idx - NQTOT;
    if (rest >= NKTOT) return;
    buf = kb;
    nh = 8;
  }
  const int j = rest & 63;
  const int hs = rest >> 6;
  const int hh = hs % nh;
  const int s = hs / nh;
  // 10000^(-j/64) = exp(-j * ln(10000)/64)
  const float inv = __expf((float)j * -0.14391157f);
  const float f = (float)s * inv;
  float sn, cs;
  __sincosf(f, &sn, &cs);
  const size_t base = (size_t)(s * nh + hh) * 128 + j;
  const float x1 = (float)buf[base];
  const float x2 = (float)buf[base + 64];
  buf[base] = (bf16)(x1 * cs - x2 * sn);
  buf[base + 64] = (bf16)(x2 * cs + x1 * sn);
}

// ---------------------------------------------------------------------------
// Flash attention, streaming (sink + local) mask — unchanged this round.
// ---------------------------------------------------------------------------
__global__ __launch_bounds__(256, 2) void attn_k(const bf16* __restrict__ q,
                                                 const bf16* __restrict__ kbuf,
                                                 const bf16* __restrict__ vT,
                                                 bf16* __restrict__ attn) {
  const int qb = 15 - blockIdx.x;
  const int h = blockIdx.y;
  const int kvh = h >> 2;
  const int tid = threadIdx.x;
  const int lane = tid & 63;
  const int w = tid >> 6;
  const int quad = lane >> 4;
  const int m16 = lane & 15;

  __shared__ bf16 Ks[4][64 * 32];
  __shared__ bf16 Vs[2][128 * 32];
  __shared__ bf16 Ps[128][72];

  const int qrow0 = qb * 128 + w * 32;

  bf16x8 qf[2][4];
#pragma unroll
  for (int rt = 0; rt < 2; ++rt)
#pragma unroll
    for (int kt = 0; kt < 4; ++kt)
      qf[rt][kt] = *(const bf16x8*)&q[(size_t)(qrow0 + rt * 16 + m16) * 4096 +
                                      h * 128 + kt * 32 + quad * 8];

  f32x4 o[2][8];
  float lsum[2][4];
#pragma unroll
  for (int rt = 0; rt < 2; ++rt) {
#pragma unroll
    for (int dt = 0; dt < 8; ++dt) o[rt][dt] = (f32x4){0.f, 0.f, 0.f, 0.f};
#pragma unroll
    for (int r = 0; r < 4; ++r) lsum[rt][r] = 0.f;
  }

  const float scale = 0.08838834764831845f;  // 1/sqrt(128)
  const bf16* kbase = kbuf + kvh * 128;
  const bf16* vbase = vT + (size_t)(kvh * 128) * 2048;

  const int klocal = (lane >> 2);
  const int kseg = (lane & 3) * 8;

  for (int b = 0; b <= qb; ++b) {
    if (b > 0 && (qb - b) >= 8) continue;  // streaming mask: sink or local
    const bool diag = (b == qb);
    for (int half = 0; half < 2; ++half) {
      const int gk0 = b * 128 + half * 64;

#pragma unroll
      for (int i = 0; i < 4; ++i) {
        const int j = w * 4 + i;
        const int kt = j >> 2, grp = (j & 3) * 16;
        load16_lds(kbase + (size_t)(gk0 + grp + klocal) * 1024 + kt * 32 + kseg,
                   &Ks[kt][grp * 32]);
      }
#pragma unroll
      for (int i = 0; i < 4; ++i) {
        const int j = w * 4 + i;
        const int kc = j >> 3, grp = (j & 7) * 16;
        load16_lds(vbase + (size_t)(grp + klocal) * 2048 + gk0 + kc * 32 + kseg,
                   &Vs[kc][grp * 32]);
      }
      __syncthreads();

      const bool skip = diag && (half * 64 > w * 32 + 31);
      if (!skip) {
        f32x4 sc[2][4];
#pragma unroll
        for (int rt = 0; rt < 2; ++rt)
#pragma unroll
          for (int ct = 0; ct < 4; ++ct)
            sc[rt][ct] = (f32x4){0.f, 0.f, 0.f, 0.f};
#pragma unroll
        for (int kt = 0; kt < 4; ++kt) {
          bf16x8 kf[4];
#pragma unroll
          for (int ct = 0; ct < 4; ++ct)
            kf[ct] = *(const bf16x8*)&Ks[kt][(ct * 16 + m16) * 32 + quad * 8];
#pragma unroll
          for (int rt = 0; rt < 2; ++rt)
#pragma unroll
            for (int ct = 0; ct < 4; ++ct)
              sc[rt][ct] = MFMA16(qf[rt][kt], kf[ct], sc[rt][ct]);
        }

#pragma unroll
        for (int rt = 0; rt < 2; ++rt)
#pragma unroll
          for (int ct = 0; ct < 4; ++ct)
#pragma unroll
            for (int r = 0; r < 4; ++r) {
              float p = __expf(sc[rt][ct][r] * scale);
              if (diag) {
                const int colg = gk0 + ct * 16 + m16;
                const int rowg = qrow0 + rt * 16 + quad * 4 + r;
                if (colg > rowg) p = 0.f;
              }
              lsum[rt][r] += p;
              Ps[w * 32 + rt * 16 + quad * 4 + r][ct * 16 + m16] = (bf16)p;
            }

#pragma unroll
        for (int rt = 0; rt < 2; ++rt)
#pragma unroll
          for (int kc = 0; kc < 2; ++kc) {
            const bf16x8 pa =
                *(const bf16x8*)&Ps[w * 32 + rt * 16 + m16][kc * 32 + quad * 8];
#pragma unroll
            for (int dt = 0; dt < 8; ++dt) {
              const bf16x8 vb =
                  *(const bf16x8*)&Vs[kc][(dt * 16 + m16) * 32 + quad * 8];
              o[rt][dt] = MFMA16(pa, vb, o[rt][dt]);
            }
          }
      }
      __syncthreads();
    }
  }

#pragma unroll
  for (int rt = 0; rt < 2; ++rt) {
    float inv[4];
#pragma unroll
    for (int r = 0; r < 4; ++r) {
      float s = lsum[rt][r];
      s += __shfl_xor(s, 1);
      s += __shfl_xor(s, 2);
      s += __shfl_xor(s, 4);
      s += __shfl_xor(s, 8);
      inv[r] = 1.0f / s;
    }
#pragma unroll
    for (int dt = 0; dt < 8; ++dt)
#pragma unroll
      for (int r = 0; r < 4; ++r)
        attn[(size_t)(qrow0 + rt * 16 + quad * 4 + r) * 4096 + h * 128 +
             dt * 16 + m16] = (bf16)(o[rt][dt][r] * inv[r]);
  }
}

// ---------------------------------------------------------------------------
// Workspace layout (88 MB; aliasing is stream-order safe):
//   off   0 MB: hiddenB (16MB)            -- dead after QKV gemm
//   off  16 MB: wqkvT  (48MB = q|k|v)     -- dead after QKV gemm
//       woT (32MB) later at off 0  (overwrites hiddenB + wqkvT head)
//       attnb (16MB) later at off 32 (overwrites wqkvT middle)
//   off  64 MB: qbuf (16MB)
//   off  80 MB: kbuf (4MB)
//   off  84 MB: vT  (4MB)
// ---------------------------------------------------------------------------
extern "C" void kernel_launch(void* const* d_in, const int* in_sizes, int n_in,
                              void* d_out, int out_size, void* d_ws,
                              size_t ws_size, hipStream_t stream) {
  const float* hidden = (const float*)d_in[0];
  const float* wq = (const float*)d_in[1];
  const float* wk = (const float*)d_in[2];
  const float* wv = (const float*)d_in[3];
  const float* wo = (const float*)d_in[4];
  float* out = (float*)d_out;

  const size_t MB = 1024 * 1024;
  bf16* hiddenB = (bf16*)d_ws;
  bf16* wqkvT = (bf16*)((char*)d_ws + 16 * MB);
  bf16* woT = (bf16*)d_ws;
  bf16* attnb = (bf16*)((char*)d_ws + 32 * MB);
  bf16* qbuf = (bf16*)((char*)d_ws + 64 * MB);
  bf16* kbuf = (bf16*)((char*)d_ws + 80 * MB);
  bf16* vT = (bf16*)((char*)d_ws + 84 * MB);

  // --- one-time casts/transposes ---
  cast_k<<<4096, 256, 0, stream>>>(hidden, hiddenB);
  transpose_cast_k<<<dim3(64, 64), 256, 0, stream>>>(wq, wqkvT, 4096, 4096);
  transpose_cast_k<<<dim3(16, 64), 256, 0, stream>>>(
      wk, wqkvT + (size_t)4096 * 4096, 4096, 1024);
  transpose_cast_k<<<dim3(16, 64), 256, 0, stream>>>(
      wv, wqkvT + (size_t)5120 * 4096, 4096, 1024);

  // --- fused QKV projection: BN=192, grid (32,8) = 256 blocks = 1/CU ---
  gemm256<bf16, 3, 2><<<dim3(32, 8), 512, 0, stream>>>(hiddenB, wqkvT, qbuf,
                                                       kbuf, vT, 4096, 4096);

  rope_k<<<(2048 * 32 * 64 + 2048 * 8 * 64) / 256, 256, 0, stream>>>(qbuf,
                                                                     kbuf);

  // woT transpose (overwrites dead hiddenB/wqkvT head)
  transpose_cast_k<<<dim3(64, 64), 256, 0, stream>>>(wo, woT, 4096, 4096);

  attn_k<<<dim3(16, 32), 256, 0, stream>>>(qbuf, kbuf, vT, attnb);

  // --- output projection: BN=128, grid (32,8) = 256 blocks = 1/CU ---
  gemm256<float, 2, 0><<<dim3(32, 8), 512, 0, stream>>>(
      attnb, woT, out, nullptr, nullptr, 4096, 4096);
}